// Round 3
// baseline (650.334 us; speedup 1.0000x reference)
//
#include <hip/hip_runtime.h>
#include <hip/hip_bf16.h>

// Problem constants (fixed by reference)
constexpr int NN   = 50000;   // nodes
constexpr int NE   = 800000;  // edges per relation
constexpr int NR   = 3;       // relations
constexpr int DIN  = 96;
constexpr int DH   = 96;
constexpr int DOUT = 64;
constexpr int SLOT = 64;      // max in-degree slots (Poisson(16): P(>64) ~ 1e-22)

// ---- bf16 helpers (RNE) ----------------------------------------------------
__device__ __forceinline__ unsigned short f2b(float f) {
    unsigned int u = __float_as_uint(f);
    u += 0x7fffu + ((u >> 16) & 1u);       // round-to-nearest-even
    return (unsigned short)(u >> 16);
}
__device__ __forceinline__ float blo(unsigned int u) { return __uint_as_float(u << 16); }
__device__ __forceinline__ float bhi(unsigned int u) { return __uint_as_float(u & 0xffff0000u); }
__device__ __forceinline__ unsigned int pack2(float lo, float hi) {
    return (unsigned int)f2b(lo) | ((unsigned int)f2b(hi) << 16);
}

// ---- f32 -> bf16 bulk convert (8 elems/thread) -----------------------------
__global__ void f32_to_bf16_kernel(const float* __restrict__ in,
                                   unsigned short* __restrict__ out, int n)
{
    int i = (blockIdx.x * 256 + threadIdx.x) * 8;
    if (i >= n) return;
    float4 a = *reinterpret_cast<const float4*>(in + i);
    float4 b = *reinterpret_cast<const float4*>(in + i + 4);
    uint4 o;
    o.x = pack2(a.x, a.y);
    o.y = pack2(a.z, a.w);
    o.z = pack2(b.x, b.y);
    o.w = pack2(b.z, b.w);
    *reinterpret_cast<uint4*>(out + i) = o;
}

// ---------------------------------------------------------------------------
// One-pass CSR build: bin src ids into fixed-size per-(relation,dst) slots.
// The count atomic's return value IS the slot index (replaces count+scan+fill).
// ---------------------------------------------------------------------------
__global__ void bin_kernel(const int* __restrict__ src,
                           const int* __restrict__ dst,
                           int* __restrict__ deg,              // [NR*NN]
                           unsigned short* __restrict__ slots) // [NR*NN][SLOT]
{
    int gid = blockIdx.x * 256 + threadIdx.x;
    if (gid >= NR * NE) return;
    int r = gid / NE;                       // compile-time divisor
    int d = dst[gid];
    int s = src[gid];
    int pos = atomicAdd(&deg[r * NN + d], 1);
    if (pos < SLOT)
        slots[((size_t)(r * NN + d)) * SLOT + pos] = (unsigned short)s;
}

// ---------------------------------------------------------------------------
// Fused layer kernel: per 16-node block
//   phase 1: gather-aggregate the 3 relations' neighbor means into LDS
//   phase 2: 3 relation GEMMs + bias + tanh, mean over relations, write once
// Input rows are bf16 [NN][96]; all math fp32.
// ---------------------------------------------------------------------------
template <int NOUT, int YR, int TM, bool OUT16>
__global__ __launch_bounds__(256)
void layer_kernel(const unsigned int* __restrict__ Hb,        // [NN][48] dwords (bf16x2)
                  const unsigned short* __restrict__ slots,   // [NR*NN][SLOT]
                  const int* __restrict__ deg,                // [NR*NN]
                  const float* __restrict__ Ws,               // [NR][96][NOUT]
                  const float* __restrict__ Wn,               // [NR][96][NOUT]
                  const float* __restrict__ bias,             // [NR][NOUT]
                  unsigned short* __restrict__ out16,         // [NN][NOUT] bf16
                  float* __restrict__ out32)                  // [NN][NOUT] f32
{
    __shared__ float xs[16][96];
    __shared__ float gs[NR][16][96];

    const int tid = threadIdx.x;
    const int n0  = blockIdx.x * 16;

    // ---- stage own 16 rows (bf16 -> f32 LDS) ----
    {
        const unsigned int* A32 = Hb + (size_t)n0 * 48;
        #pragma unroll
        for (int k = 0; k < 3; ++k) {
            int i = tid + k * 256;          // 768 dwords total
            unsigned int u = A32[i];
            int row = i / 48, col = i % 48;
            xs[row][2 * col]     = blo(u);
            xs[row][2 * col + 1] = bhi(u);
        }
    }

    // ---- gather-aggregate: 16 lanes per node, 3 relations ----
    {
        const int gl = tid >> 4;            // local node 0..15
        const int t  = tid & 15;
        const int g  = n0 + gl;
        for (int r = 0; r < NR; ++r) {
            const unsigned short* sl = slots + ((size_t)(r * NN + g)) * SLOT;
            int e = deg[r * NN + g];
            if (e > SLOT) e = SLOT;
            float a0 = 0.f, a1 = 0.f, a2 = 0.f, a3 = 0.f, a4 = 0.f, a5 = 0.f;
            int i = 0;
            for (; i + 1 < e; i += 2) {
                int s0 = sl[i], s1 = sl[i + 1];
                const unsigned int* r0 = Hb + (size_t)s0 * 48;
                const unsigned int* r1 = Hb + (size_t)s1 * 48;
                unsigned int u0 = r0[t], u1 = r0[t + 16], u2 = r0[t + 32];
                unsigned int v0 = r1[t], v1 = r1[t + 16], v2 = r1[t + 32];
                a0 += blo(u0) + blo(v0); a1 += bhi(u0) + bhi(v0);
                a2 += blo(u1) + blo(v1); a3 += bhi(u1) + bhi(v1);
                a4 += blo(u2) + blo(v2); a5 += bhi(u2) + bhi(v2);
            }
            if (i < e) {
                const unsigned int* r0 = Hb + (size_t)sl[i] * 48;
                unsigned int u0 = r0[t], u1 = r0[t + 16], u2 = r0[t + 32];
                a0 += blo(u0); a1 += bhi(u0);
                a2 += blo(u1); a3 += bhi(u1);
                a4 += blo(u2); a5 += bhi(u2);
            }
            float inv = 1.0f / (float)(e > 0 ? e : 1);
            gs[r][gl][2 * t]      = a0 * inv;
            gs[r][gl][2 * t + 1]  = a1 * inv;
            gs[r][gl][2 * t + 32] = a2 * inv;
            gs[r][gl][2 * t + 33] = a3 * inv;
            gs[r][gl][2 * t + 64] = a4 * inv;
            gs[r][gl][2 * t + 65] = a5 * inv;
        }
    }
    __syncthreads();

    // ---- 3-relation GEMM + tanh + mean ----
    if (tid < NOUT * YR) {
        const int tx = tid % NOUT;
        const int ty = tid / NOUT;
        const int row0 = ty * TM;

        float res[TM];
        #pragma unroll
        for (int j = 0; j < TM; ++j) res[j] = 0.f;

        for (int r = 0; r < NR; ++r) {
            const float* Wsr = Ws + (size_t)r * 96 * NOUT;
            const float* Wnr = Wn + (size_t)r * 96 * NOUT;
            float acc[TM];
            #pragma unroll
            for (int j = 0; j < TM; ++j) acc[j] = 0.f;

            for (int d4 = 0; d4 < 96; d4 += 4) {
                float xr[TM][4], gr[TM][4];
                #pragma unroll
                for (int j = 0; j < TM; ++j) {
                    float4 t1 = *reinterpret_cast<const float4*>(&xs[row0 + j][d4]);
                    float4 t2 = *reinterpret_cast<const float4*>(&gs[r][row0 + j][d4]);
                    xr[j][0] = t1.x; xr[j][1] = t1.y; xr[j][2] = t1.z; xr[j][3] = t1.w;
                    gr[j][0] = t2.x; gr[j][1] = t2.y; gr[j][2] = t2.z; gr[j][3] = t2.w;
                }
                #pragma unroll
                for (int dd = 0; dd < 4; ++dd) {
                    float wsv = Wsr[(d4 + dd) * NOUT + tx];
                    float wnv = Wnr[(d4 + dd) * NOUT + tx];
                    #pragma unroll
                    for (int j = 0; j < TM; ++j)
                        acc[j] += xr[j][dd] * wsv + gr[j][dd] * wnv;
                }
            }
            const float bb = bias[r * NOUT + tx];
            #pragma unroll
            for (int j = 0; j < TM; ++j)
                res[j] += tanhf(acc[j] + bb);
        }

        const float third = 1.0f / (float)NR;
        #pragma unroll
        for (int j = 0; j < TM; ++j) {
            const int n = n0 + row0 + j;
            float v = res[j] * third;
            if (OUT16) out16[(size_t)n * NOUT + tx] = f2b(v);
            else       out32[(size_t)n * NOUT + tx] = v;
        }
    }
}

// ---------------------------------------------------------------------------
extern "C" void kernel_launch(void* const* d_in, const int* in_sizes, int n_in,
                              void* d_out, int out_size, void* d_ws, size_t ws_size,
                              hipStream_t stream)
{
    const float* x   = (const float*)d_in[0];
    const int*   src = (const int*)d_in[1];
    const int*   dst = (const int*)d_in[2];
    const float* Ws1 = (const float*)d_in[3];
    const float* Wn1 = (const float*)d_in[4];
    const float* b1  = (const float*)d_in[5];
    const float* Ws2 = (const float*)d_in[6];
    const float* Wn2 = (const float*)d_in[7];
    const float* b2  = (const float*)d_in[8];
    float* out = (float*)d_out;

    // Workspace layout (256B-aligned), ~39 MB total.
    char* ws = (char*)d_ws;
    size_t o = 0;
    auto alloc = [&](size_t bytes) {
        size_t p = o;
        o += (bytes + 255) & ~(size_t)255;
        return p;
    };
    int* deg = (int*)(ws + alloc((size_t)NR * NN * 4));                       // 0.6 MB
    unsigned short* slots = (unsigned short*)(ws + alloc((size_t)NR * NN * SLOT * 2)); // 19.2 MB
    unsigned short* xb  = (unsigned short*)(ws + alloc((size_t)NN * 96 * 2)); // 9.6 MB
    unsigned short* h1b = (unsigned short*)(ws + alloc((size_t)NN * 96 * 2)); // 9.6 MB

    // x -> bf16 (independent of CSR build)
    f32_to_bf16_kernel<<<(NN * 96 / 8 + 255) / 256, 256, 0, stream>>>(x, xb, NN * 96);

    // one-pass binned-CSR build
    hipMemsetAsync(deg, 0, (size_t)NR * NN * 4, stream);
    bin_kernel<<<(NR * NE + 255) / 256, 256, 0, stream>>>(src, dst, deg, slots);

    // Layer 1: h1 = mean_r tanh(x@Ws1_r + mean-agg_r(x)@Wn1_r + b1_r)  -> bf16
    layer_kernel<DH, 2, 8, true><<<NN / 16, 256, 0, stream>>>(
        (const unsigned int*)xb, slots, deg, Ws1, Wn1, b1, h1b, (float*)nullptr);

    // Layer 2: out = mean_r tanh(h1@Ws2_r + mean-agg_r(h1)@Wn2_r + b2_r) -> f32
    layer_kernel<DOUT, 4, 4, false><<<NN / 16, 256, 0, stream>>>(
        (const unsigned int*)h1b, slots, deg, Ws2, Wn2, b2,
        (unsigned short*)nullptr, out);
}